// Round 1
// 1418.912 us; speedup vs baseline: 1.0613x; 1.0613x over previous
//
#include <hip/hip_runtime.h>
#include <hip/hip_bf16.h>
#include <math.h>

// Problem constants
#define HIDN  4096
#define NH    32
#define HD    128
#define NB    4
#define NT    16
#define SPAST 4096
#define STOT  4112
#define NCHUNK 8        // chunks 0..6: 512 rows, chunk 7: 528 rows (incl. 16 new)

// ws layout (float offsets)
#define WS_Q    0
#define WS_CTX  262144
#define WS_PART 524288
#define PART_STRIDE 2080  // 16*128 o + 16 m + 16 l

typedef float f32x4 __attribute__((ext_vector_type(4)));
typedef short bf16x8 __attribute__((ext_vector_type(8)));  // 8 bf16 (4 VGPRs)

// Packed RNE fp32->bf16 (v_cvt_pk_bf16_f32), same rounding as previous manual RNE.
__device__ __forceinline__ bf16x8 load_bf16x8(const float* p) {
    const float4* p4 = (const float4*)p;
    float4 a = p4[0], b = p4[1];
    union { __hip_bfloat162 h[4]; bf16x8 v; } r;
    r.h[0] = __float22bfloat162_rn(make_float2(a.x, a.y));
    r.h[1] = __float22bfloat162_rn(make_float2(a.z, a.w));
    r.h[2] = __float22bfloat162_rn(make_float2(b.x, b.y));
    r.h[3] = __float22bfloat162_rn(make_float2(b.z, b.w));
    return r.v;
}

// C = A(64xK) @ W(NxK)^T via bf16 MFMA, fp32 accum.
// One wave per 16x16 output tile: wave index = m-subtile, 16 cols per block.
// grid (256, 3) for QKV / (256, 1) for out-proj -> 3072 / 1024 waves.
// blockIdx.y: y==0 row-major C; y>0 scatter into kv-cache layout [b,h,SPAST+t,d]
__global__ __launch_bounds__(256) void gemm64_kernel(
    const float* __restrict__ A,
    const float* __restrict__ w0, const float* __restrict__ w1, const float* __restrict__ w2,
    float* __restrict__ c0, float* __restrict__ c1, float* __restrict__ c2)
{
    const int mi   = threadIdx.x >> 6;   // wave owns m-subtile mi (rows mi*16..mi*16+15)
    const int lane = threadIdx.x & 63;
    const int l16  = lane & 15;
    const int quad = lane >> 4;
    const int y = blockIdx.y;
    const float* W = (y == 0) ? w0 : (y == 1) ? w1 : w2;
    float*       C = (y == 0) ? c0 : (y == 1) ? c1 : c2;

    const int n = blockIdx.x * 16 + l16;                    // output column / W row
    const float* wrow = W + (size_t)n * HIDN + quad * 8;
    const float* arow = A + (size_t)(mi * 16 + l16) * HIDN + quad * 8;

    f32x4 acc = {};
#pragma unroll 4
    for (int k0 = 0; k0 < HIDN; k0 += 32) {
        bf16x8 bfrag = load_bf16x8(wrow + k0);
        bf16x8 afrag = load_bf16x8(arow + k0);
        acc = __builtin_amdgcn_mfma_f32_16x16x32_bf16(afrag, bfrag, acc, 0, 0, 0);
    }
    // C/D layout: col = lane&15, row = quad*4 + reg  [m89-verified]
#pragma unroll
    for (int r = 0; r < 4; ++r) {
        int m = mi * 16 + quad * 4 + r;
        if (y == 0) {
            C[(size_t)m * HIDN + n] = acc[r];
        } else {
            int b = m >> 4, t = m & 15, h = n >> 7, d = n & 127;
            C[((size_t)(b * NH + h) * STOT + SPAST + t) * HD + d] = acc[r];
        }
    }
}

// Split-S flash attention partials, FUSED with the cache->full concat copy:
// reads cache_k/cache_v (past rows) exactly once, stores them to k_full/v_full
// from registers while computing. New rows (s>=SPAST) were written by the QKV
// gemm directly into the k_full/v_full tails and are read from there.
// grid (128 bh, NCHUNK). 256 threads.
__global__ __launch_bounds__(256) void attn_partial_kernel(
    const float* __restrict__ qp,   // ws q_proj 64x4096
    const float* __restrict__ ck,   // cache_k [bh, SPAST, HD]
    const float* __restrict__ cv,   // cache_v
    float* __restrict__ kf,         // k_full (in d_out)
    float* __restrict__ vf,         // v_full (in d_out)
    float* __restrict__ part)
{
    __shared__ float qs[16][128];
    __shared__ float sc[16][257];
    __shared__ float red[16][16];
    __shared__ float m_run[16], l_run[16], alpha_s[16];

    const int tid = threadIdx.x;
    const int bh  = blockIdx.x;
    const int c   = blockIdx.y;
    const int b = bh >> 5, h = bh & 31;
    const int s_beg = c * 512;
    const int s_end = (c == NCHUNK - 1) ? STOT : (s_beg + 512);

    const float scale = 0.08838834764831845f;  // 1/sqrt(128)
    for (int i = tid; i < 16 * 128; i += 256) {
        int t = i >> 7, d = i & 127;
        qs[t][d] = qp[(size_t)(b * 16 + t) * HIDN + h * 128 + d] * scale;
    }
    if (tid < 16) { m_run[tid] = -INFINITY; l_run[tid] = 0.f; }
    __syncthreads();

    const int tg = tid >> 4;   // t owned in reduce/PV phases
    const int ig = tid & 15;
    float o_loc[8];
#pragma unroll
    for (int i = 0; i < 8; ++i) o_loc[i] = 0.f;

    for (int s0 = s_beg; s0 < s_end; s0 += 256) {
        const int tile_n = min(256, s_end - s0);
        const bool is_new = (s0 >= SPAST);   // tile-uniform: chunks align new rows to own tile
        // ---- scores: thread j owns s = s0+j; copy K row cache->full on the fly
        if (tid < tile_n) {
            const int s = s0 + tid;
            const float* krow = is_new ? (kf + ((size_t)bh * STOT  + s) * HD)
                                       : (ck + ((size_t)bh * SPAST + s) * HD);
            float* kdst = kf + ((size_t)bh * STOT + s) * HD;
            float scr[16];
#pragma unroll
            for (int t = 0; t < 16; ++t) scr[t] = 0.f;
            for (int dc = 0; dc < 128; dc += 32) {
                float4 kb[8];
#pragma unroll
                for (int u = 0; u < 8; ++u) kb[u] = ((const float4*)(krow + dc))[u];
                if (!is_new) {
#pragma unroll
                    for (int u = 0; u < 8; ++u) ((float4*)(kdst + dc))[u] = kb[u];
                }
#pragma unroll
                for (int t = 0; t < 16; ++t) {
                    float s4 = 0.f;
#pragma unroll
                    for (int u = 0; u < 8; ++u) {
                        float4 qv = ((const float4*)&qs[t][dc])[u];
                        s4 += qv.x * kb[u].x + qv.y * kb[u].y + qv.z * kb[u].z + qv.w * kb[u].w;
                    }
                    scr[t] += s4;
                }
            }
#pragma unroll
            for (int t = 0; t < 16; ++t) sc[t][tid] = scr[t];
        }
        __syncthreads();
        // ---- per-t tile max
        {
            float pm = -INFINITY;
            for (int j = ig; j < tile_n; j += 16) pm = fmaxf(pm, sc[tg][j]);
            red[tg][ig] = pm;
        }
        __syncthreads();
        if (tid < 16) {
            float tmax = -INFINITY;
#pragma unroll
            for (int i = 0; i < 16; ++i) tmax = fmaxf(tmax, red[tid][i]);
            float mo = m_run[tid];
            float mn = fmaxf(mo, tmax);
            alpha_s[tid] = __expf(mo - mn);
            m_run[tid] = mn;
        }
        __syncthreads();
        // ---- exp + tile sum
        {
            float ps = 0.f;
            const float mn = m_run[tg];
            for (int j = ig; j < tile_n; j += 16) {
                float p = __expf(sc[tg][j] - mn);
                sc[tg][j] = p;
                ps += p;
            }
            red[tg][ig] = ps;
        }
        __syncthreads();
        if (tid < 16) {
            float ts = 0.f;
#pragma unroll
            for (int i = 0; i < 16; ++i) ts += red[tid][i];
            l_run[tid] = l_run[tid] * alpha_s[tid] + ts;
        }
        __syncthreads();
        // ---- rescale + PV: thread owns (t=tg, d=ig*8..ig*8+7); copy V row on the fly
        {
            const float al = alpha_s[tg];
#pragma unroll
            for (int i = 0; i < 8; ++i) o_loc[i] *= al;
            const float* vsrc = is_new ? (vf + ((size_t)bh * STOT  + s0) * HD)
                                       : (cv + ((size_t)bh * SPAST + s0) * HD);
            float* vdst = vf + ((size_t)bh * STOT + s0) * HD;
            for (int j = 0; j < tile_n; ++j) {
                float p = sc[tg][j];
                const float4* vr = (const float4*)(vsrc + (size_t)j * HD + ig * 8);
                float4 v0 = vr[0], v1 = vr[1];
                if (!is_new && ((j & 15) == tg)) {
                    // t-group (j mod 16) owns the v_full store of row j: 16 lanes x 16B
                    float4* vw = (float4*)(vdst + (size_t)j * HD + ig * 8);
                    vw[0] = v0; vw[1] = v1;
                }
                o_loc[0] += p * v0.x; o_loc[1] += p * v0.y;
                o_loc[2] += p * v0.z; o_loc[3] += p * v0.w;
                o_loc[4] += p * v1.x; o_loc[5] += p * v1.y;
                o_loc[6] += p * v1.z; o_loc[7] += p * v1.w;
            }
        }
        __syncthreads();   // sc reused next tile
    }
    float* pp = part + ((size_t)bh * NCHUNK + c) * PART_STRIDE;
#pragma unroll
    for (int i = 0; i < 8; ++i) pp[tg * 128 + ig * 8 + i] = o_loc[i];
    if (tid < 16) { pp[2048 + tid] = m_run[tid]; pp[2064 + tid] = l_run[tid]; }
}

// Merge NCHUNK partials -> ctx (64x4096 row-major in ws)
__global__ __launch_bounds__(256) void combine_kernel(
    const float* __restrict__ part, float* __restrict__ ctx)
{
    const int bh = blockIdx.x;
    const int tid = threadIdx.x;
    const int t = tid >> 4, i = tid & 15;
    const int b = bh >> 5, h = bh & 31;
    const float* pb = part + (size_t)bh * NCHUNK * PART_STRIDE;

    float M = -INFINITY;
#pragma unroll
    for (int cI = 0; cI < NCHUNK; ++cI) M = fmaxf(M, pb[cI * PART_STRIDE + 2048 + t]);
    float L = 0.f;
    float w[NCHUNK];
#pragma unroll
    for (int cI = 0; cI < NCHUNK; ++cI) {
        float e = __expf(pb[cI * PART_STRIDE + 2048 + t] - M);
        w[cI] = e;
        L += e * pb[cI * PART_STRIDE + 2064 + t];
    }
    const float invL = 1.f / L;
    float o[8];
#pragma unroll
    for (int k = 0; k < 8; ++k) o[k] = 0.f;
#pragma unroll
    for (int cI = 0; cI < NCHUNK; ++cI) {
        const float* po = pb + cI * PART_STRIDE + t * 128 + i * 8;
        const float wc = w[cI];
#pragma unroll
        for (int k = 0; k < 8; ++k) o[k] += wc * po[k];
    }
    float* dst = ctx + (size_t)(b * 16 + t) * HIDN + h * 128 + i * 8;
#pragma unroll
    for (int k = 0; k < 8; ++k) dst[k] = o[k] * invL;
}

extern "C" void kernel_launch(void* const* d_in, const int* in_sizes, int n_in,
                              void* d_out, int out_size, void* d_ws, size_t ws_size,
                              hipStream_t stream) {
    const float* hidden  = (const float*)d_in[0];
    const float* cache_k = (const float*)d_in[1];
    const float* cache_v = (const float*)d_in[2];
    const float* wq = (const float*)d_in[3];
    const float* wk = (const float*)d_in[4];
    const float* wv = (const float*)d_in[5];
    const float* wo = (const float*)d_in[6];

    float* out   = (float*)d_out;            // 64*4096
    float* kfull = out + 262144;             // 128*4112*128
    float* vfull = kfull + 67371008LL;

    float* ws   = (float*)d_ws;
    float* qp   = ws + WS_Q;
    float* ctx  = ws + WS_CTX;
    float* part = ws + WS_PART;

    // 1. QKV projections; K/V new rows written directly into k_full/v_full tails
    gemm64_kernel<<<dim3(256, 3), 256, 0, stream>>>(hidden, wq, wk, wv, qp, kfull, vfull);
    // 2. split-S flash attention partials, fused with cache->full concat copy
    attn_partial_kernel<<<dim3(128, NCHUNK), 256, 0, stream>>>(
        qp, cache_k, cache_v, kfull, vfull, part);
    // 3. combine partials -> ctx
    combine_kernel<<<dim3(128), 256, 0, stream>>>(part, ctx);
    // 4. output projection
    gemm64_kernel<<<dim3(256, 1), 256, 0, stream>>>(ctx, wo, wo, wo, out, nullptr, nullptr);
}

// Round 2
// 1358.005 us; speedup vs baseline: 1.1089x; 1.0448x over previous
//
#include <hip/hip_runtime.h>
#include <hip/hip_bf16.h>
#include <math.h>

// Problem constants
#define HIDN  4096
#define NH    32
#define HD    128
#define NB    4
#define NT    16
#define SPAST 4096
#define STOT  4112
#define NCHUNK 12       // 1536 blocks = exactly 6 blocks/CU (LDS-capped residency)
#define CHUNK 344       // chunks 0..10: 344 rows; chunk 11: 328 rows (incl. 16 new)

// ws layout (float offsets)
#define WS_Q    0
#define WS_CTX  262144
#define WS_PART 524288
#define PART_STRIDE 2080  // 16*128 o + 16 m + 16 l

typedef float f32x4 __attribute__((ext_vector_type(4)));
typedef short bf16x8 __attribute__((ext_vector_type(8)));  // 8 bf16 (4 VGPRs)

// Packed RNE fp32->bf16 (v_cvt_pk_bf16_f32), same rounding as manual RNE.
__device__ __forceinline__ bf16x8 load_bf16x8(const float* p) {
    const float4* p4 = (const float4*)p;
    float4 a = p4[0], b = p4[1];
    union { __hip_bfloat162 h[4]; bf16x8 v; } r;
    r.h[0] = __float22bfloat162_rn(make_float2(a.x, a.y));
    r.h[1] = __float22bfloat162_rn(make_float2(a.z, a.w));
    r.h[2] = __float22bfloat162_rn(make_float2(b.x, b.y));
    r.h[3] = __float22bfloat162_rn(make_float2(b.z, b.w));
    return r.v;
}

// C = A(64xK) @ W(NxK)^T via bf16 MFMA, fp32 accum.
// One wave per 16x16 output tile. grid (256, 3) QKV / (256, 1) out-proj.
// blockIdx.y: y==0 row-major C; y>0 scatter into kv-cache layout [b,h,SPAST+t,d]
__global__ __launch_bounds__(256) void gemm64_kernel(
    const float* __restrict__ A,
    const float* __restrict__ w0, const float* __restrict__ w1, const float* __restrict__ w2,
    float* __restrict__ c0, float* __restrict__ c1, float* __restrict__ c2)
{
    const int mi   = threadIdx.x >> 6;
    const int lane = threadIdx.x & 63;
    const int l16  = lane & 15;
    const int quad = lane >> 4;
    const int y = blockIdx.y;
    const float* W = (y == 0) ? w0 : (y == 1) ? w1 : w2;
    float*       C = (y == 0) ? c0 : (y == 1) ? c1 : c2;

    const int n = blockIdx.x * 16 + l16;
    const float* wrow = W + (size_t)n * HIDN + quad * 8;
    const float* arow = A + (size_t)(mi * 16 + l16) * HIDN + quad * 8;

    f32x4 acc = {};
#pragma unroll 4
    for (int k0 = 0; k0 < HIDN; k0 += 32) {
        bf16x8 bfrag = load_bf16x8(wrow + k0);
        bf16x8 afrag = load_bf16x8(arow + k0);
        acc = __builtin_amdgcn_mfma_f32_16x16x32_bf16(afrag, bfrag, acc, 0, 0, 0);
    }
    // C/D layout: col = lane&15, row = quad*4 + reg  [m89-verified]
#pragma unroll
    for (int r = 0; r < 4; ++r) {
        int m = mi * 16 + quad * 4 + r;
        if (y == 0) {
            C[(size_t)m * HIDN + n] = acc[r];
        } else {
            int b = m >> 4, t = m & 15, h = n >> 7, d = n & 127;
            C[((size_t)(b * NH + h) * STOT + SPAST + t) * HD + d] = acc[r];
        }
    }
}

// Split-S flash attention, fused with the cache->full concat copy.
// Coalesced K path: 4 lanes per row, interleaved d-split, shfl_xor reduce.
// grid (128 bh, NCHUNK). 256 threads.
__global__ __launch_bounds__(256, 6) void attn_partial_kernel(
    const float* __restrict__ qp,   // ws q_proj 64x4096
    const float* __restrict__ ck,   // cache_k [bh, SPAST, HD]
    const float* __restrict__ cv,   // cache_v
    float* __restrict__ kf,         // k_full (in d_out)
    float* __restrict__ vf,         // v_full (in d_out)
    float* __restrict__ part)
{
    __shared__ float qs[16][128];
    __shared__ float sc[16][260];   // 260: float4-aligned rows, +4-bank row skew
    __shared__ float red[16][16];
    __shared__ float m_run[16], l_run[16], alpha_s[16];

    const int tid = threadIdx.x;
    const int bh  = blockIdx.x;
    const int c   = blockIdx.y;
    const int b = bh >> 5, h = bh & 31;
    const int s_beg = c * CHUNK;
    const int s_end = min(s_beg + CHUNK, STOT);

    const float scale = 0.08838834764831845f;  // 1/sqrt(128)
    for (int i = tid; i < 16 * 128; i += 256) {
        int t = i >> 7, d = i & 127;
        qs[t][d] = qp[(size_t)(b * 16 + t) * HIDN + h * 128 + d] * scale;
    }
    if (tid < 16) { m_run[tid] = -INFINITY; l_run[tid] = 0.f; }
    __syncthreads();

    const int tg = tid >> 4;   // t owned in reduce/PV phases
    const int ig = tid & 15;
    const int q4 = tid & 3;    // d-quarter in score phase (interleaved)
    float o_loc[8];
#pragma unroll
    for (int i = 0; i < 8; ++i) o_loc[i] = 0.f;

    for (int s0 = s_beg; s0 < s_end; s0 += 256) {
        const int tile_n = min(256, s_end - s0);
        // ---- scores: 4 lanes per K row (d = u*16 + q4*4), coalesced load + copy
#pragma unroll
        for (int s_sub = 0; s_sub < 4; ++s_sub) {
            const int j = s_sub * 64 + (tid >> 2);
            if (j < tile_n) {
                const int s = s0 + j;
                const float* krow = (s < SPAST) ? (ck + ((size_t)bh * SPAST + s) * HD)
                                                : (kf + ((size_t)bh * STOT  + s) * HD);
                float4 kb[8];
#pragma unroll
                for (int u = 0; u < 8; ++u)
                    kb[u] = *(const float4*)(krow + u * 16 + q4 * 4);
                if (s < SPAST) {
                    float* kdst = kf + ((size_t)bh * STOT + s) * HD;
#pragma unroll
                    for (int u = 0; u < 8; ++u)
                        *(float4*)(kdst + u * 16 + q4 * 4) = kb[u];
                }
#pragma unroll
                for (int t = 0; t < 16; ++t) {
                    float s4 = 0.f;
#pragma unroll
                    for (int u = 0; u < 8; ++u) {
                        float4 qv = *(const float4*)(&qs[t][u * 16 + q4 * 4]);
                        s4 += qv.x * kb[u].x + qv.y * kb[u].y + qv.z * kb[u].z + qv.w * kb[u].w;
                    }
                    s4 += __shfl_xor(s4, 1, 64);
                    s4 += __shfl_xor(s4, 2, 64);
                    if (q4 == 0) sc[t][j] = s4;
                }
            }
        }
        __syncthreads();
        // ---- per-t tile max
        {
            float pm = -INFINITY;
            for (int j = ig; j < tile_n; j += 16) pm = fmaxf(pm, sc[tg][j]);
            red[tg][ig] = pm;
        }
        __syncthreads();
        if (tid < 16) {
            float tmax = -INFINITY;
#pragma unroll
            for (int i = 0; i < 16; ++i) tmax = fmaxf(tmax, red[tid][i]);
            float mo = m_run[tid];
            float mn = fmaxf(mo, tmax);
            alpha_s[tid] = __expf(mo - mn);
            m_run[tid] = mn;
        }
        __syncthreads();
        // ---- exp + tile sum
        {
            float ps = 0.f;
            const float mn = m_run[tg];
            for (int j = ig; j < tile_n; j += 16) {
                float p = __expf(sc[tg][j] - mn);
                sc[tg][j] = p;
                ps += p;
            }
            red[tg][ig] = ps;
        }
        __syncthreads();
        if (tid < 16) {
            float ts = 0.f;
#pragma unroll
            for (int i = 0; i < 16; ++i) ts += red[tid][i];
            l_run[tid] = l_run[tid] * alpha_s[tid] + ts;
        }
        __syncthreads();
        // ---- rescale + PV: thread owns (t=tg, d=ig*8..+7); copy V rows on the fly
        {
            const float al = alpha_s[tg];
#pragma unroll
            for (int i = 0; i < 8; ++i) o_loc[i] *= al;
            for (int j0 = 0; j0 < tile_n; j0 += 4) {
                float4 p4 = *(const float4*)&sc[tg][j0];
#pragma unroll
                for (int jj = 0; jj < 4; ++jj) {
                    const int j = j0 + jj;
                    const int s = s0 + j;
                    const float p = (jj == 0) ? p4.x : (jj == 1) ? p4.y : (jj == 2) ? p4.z : p4.w;
                    const float* vrow = (s < SPAST) ? (cv + ((size_t)bh * SPAST + s) * HD)
                                                    : (vf + ((size_t)bh * STOT  + s) * HD);
                    const float4* vr = (const float4*)(vrow + ig * 8);
                    float4 v0 = vr[0], v1 = vr[1];
                    if (s < SPAST && ((j & 15) == tg)) {
                        float4* vw = (float4*)(vf + ((size_t)bh * STOT + s) * HD + ig * 8);
                        vw[0] = v0; vw[1] = v1;
                    }
                    o_loc[0] += p * v0.x; o_loc[1] += p * v0.y;
                    o_loc[2] += p * v0.z; o_loc[3] += p * v0.w;
                    o_loc[4] += p * v1.x; o_loc[5] += p * v1.y;
                    o_loc[6] += p * v1.z; o_loc[7] += p * v1.w;
                }
            }
        }
        __syncthreads();   // sc reused next tile
    }
    float* pp = part + ((size_t)bh * NCHUNK + c) * PART_STRIDE;
#pragma unroll
    for (int i = 0; i < 8; ++i) pp[tg * 128 + ig * 8 + i] = o_loc[i];
    if (tid < 16) { pp[2048 + tid] = m_run[tid]; pp[2064 + tid] = l_run[tid]; }
}

// Merge NCHUNK partials -> ctx (64x4096 row-major in ws)
__global__ __launch_bounds__(256) void combine_kernel(
    const float* __restrict__ part, float* __restrict__ ctx)
{
    const int bh = blockIdx.x;
    const int tid = threadIdx.x;
    const int t = tid >> 4, i = tid & 15;
    const int b = bh >> 5, h = bh & 31;
    const float* pb = part + (size_t)bh * NCHUNK * PART_STRIDE;

    float M = -INFINITY;
#pragma unroll
    for (int cI = 0; cI < NCHUNK; ++cI) M = fmaxf(M, pb[cI * PART_STRIDE + 2048 + t]);
    float L = 0.f;
    float w[NCHUNK];
#pragma unroll
    for (int cI = 0; cI < NCHUNK; ++cI) {
        float e = __expf(pb[cI * PART_STRIDE + 2048 + t] - M);
        w[cI] = e;
        L += e * pb[cI * PART_STRIDE + 2064 + t];
    }
    const float invL = 1.f / L;
    float o[8];
#pragma unroll
    for (int k = 0; k < 8; ++k) o[k] = 0.f;
#pragma unroll
    for (int cI = 0; cI < NCHUNK; ++cI) {
        const float* po = pb + cI * PART_STRIDE + t * 128 + i * 8;
        const float wc = w[cI];
#pragma unroll
        for (int k = 0; k < 8; ++k) o[k] += wc * po[k];
    }
    float* dst = ctx + (size_t)(b * 16 + t) * HIDN + h * 128 + i * 8;
#pragma unroll
    for (int k = 0; k < 8; ++k) dst[k] = o[k] * invL;
}

extern "C" void kernel_launch(void* const* d_in, const int* in_sizes, int n_in,
                              void* d_out, int out_size, void* d_ws, size_t ws_size,
                              hipStream_t stream) {
    const float* hidden  = (const float*)d_in[0];
    const float* cache_k = (const float*)d_in[1];
    const float* cache_v = (const float*)d_in[2];
    const float* wq = (const float*)d_in[3];
    const float* wk = (const float*)d_in[4];
    const float* wv = (const float*)d_in[5];
    const float* wo = (const float*)d_in[6];

    float* out   = (float*)d_out;            // 64*4096
    float* kfull = out + 262144;             // 128*4112*128
    float* vfull = kfull + 67371008LL;

    float* ws   = (float*)d_ws;
    float* qp   = ws + WS_Q;
    float* ctx  = ws + WS_CTX;
    float* part = ws + WS_PART;

    // 1. QKV projections; K/V new rows written directly into k_full/v_full tails
    gemm64_kernel<<<dim3(256, 3), 256, 0, stream>>>(hidden, wq, wk, wv, qp, kfull, vfull);
    // 2. split-S flash attention partials, fused with cache->full concat copy
    attn_partial_kernel<<<dim3(128, NCHUNK), 256, 0, stream>>>(
        qp, cache_k, cache_v, kfull, vfull, part);
    // 3. combine partials -> ctx
    combine_kernel<<<dim3(128), 256, 0, stream>>>(part, ctx);
    // 4. output projection
    gemm64_kernel<<<dim3(256, 1), 256, 0, stream>>>(ctx, wo, wo, wo, out, nullptr, nullptr);
}